// Round 10
// baseline (284.932 us; speedup 1.0000x reference)
//
#include <hip/hip_runtime.h>
#include <hip/hip_bf16.h>

namespace {

constexpr int kVocab = 100000;
constexpr int kS     = 13;     // sequence / n_feat
constexpr int kH     = 128;    // hidden
constexpr int kBatch = 16384;

// main kernel geometry
constexpr int kMainGrid   = 1024;
constexpr int kRowsPerBlk = kBatch / kMainGrid;   // 16

// prep geometry
constexpr int kPrepBlocks = 2049;                 // block 0: weights+seeds; 1..: table
constexpr int kTabChunks  = kVocab * kH / 8;      // 1,600,000 bf16x8 chunks

// ws layout (bytes)
constexpr size_t kTabBytes  = (size_t)kVocab * kH * 2;   // 25,600,000
constexpr size_t kWpkOff    = kTabBytes;
constexpr size_t kWpkBytes  = (size_t)3*2*4 * 256 * 16;  // 98,304
constexpr size_t kSeedOff   = kWpkOff + kWpkBytes;
constexpr size_t kSeedBytes = (size_t)3*2*4*64 * 16;     // 24,576
constexpr size_t kWsNeed    = kSeedOff + kSeedBytes;     // ~25.7 MB

typedef __attribute__((ext_vector_type(8))) short bf16x8;
typedef __attribute__((ext_vector_type(4))) float f32x4;

__device__ __forceinline__ short f2b(float f) {
  __hip_bfloat16 h = __float2bfloat16(f);
  return __builtin_bit_cast(short, h);
}
// pack two D-fragments (nt=0, nt=1) into one MFMA A/B-operand; k-slot 8g+i
// maps to d = 16*(i>>2)+4g+(i&3) — the same bijection on both operands of the
// scores MFMA, so the dot product is exact (verified R5/R8, absmax 4.9e-4).
__device__ __forceinline__ bf16x8 pack8(f32x4 lo, f32x4 hi) {
  bf16x8 r;
  r[0]=f2b(lo[0]); r[1]=f2b(lo[1]); r[2]=f2b(lo[2]); r[3]=f2b(lo[3]);
  r[4]=f2b(hi[0]); r[5]=f2b(hi[1]); r[6]=f2b(hi[2]); r[7]=f2b(hi[3]);
  return r;
}

// ---------------------------------------------------------------------------
// Prep: block 0 packs weight fragments (0.5 folded) + seeds (feat/2 @ W^T + b)
// once; blocks 1.. convert the vocab table to bf16 (streaming, coalesced).
// ---------------------------------------------------------------------------
__global__ __launch_bounds__(256)
void fsa_prep(const float* __restrict__ num_emb, const float* __restrict__ feat_emb,
              const float* __restrict__ Wq, const float* __restrict__ bq,
              const float* __restrict__ Wk, const float* __restrict__ bk,
              const float* __restrict__ Wv, const float* __restrict__ bv,
              unsigned char* __restrict__ ws)
{
  const int tid = threadIdx.x;
  if (blockIdx.x == 0) {
    const int lane = tid & 63, h = tid >> 6, l15 = lane & 15, g = lane >> 4;
    const int sIdx = (l15 < 13) ? l15 : 12;
    bf16x8* wpk   = (bf16x8*)(ws + kWpkOff);
    f32x4*  seeds = (f32x4*) (ws + kSeedOff);

    bf16x8 bfrag[3][2][4];
    const float* Wmat[3] = {Wq, Wk, Wv};
#pragma unroll
    for (int m = 0; m < 3; ++m)
#pragma unroll
      for (int nt = 0; nt < 2; ++nt) {
        const int n = 32*h + 16*nt + l15;
#pragma unroll
        for (int kk = 0; kk < 4; ++kk) {
          const float* p = Wmat[m] + n * kH + kk*32 + g*8;
          const float4 x0 = *(const float4*)p;
          const float4 x1 = *(const float4*)(p + 4);
          bf16x8 fr;
          fr[0]=f2b(x0.x*0.5f); fr[1]=f2b(x0.y*0.5f);
          fr[2]=f2b(x0.z*0.5f); fr[3]=f2b(x0.w*0.5f);
          fr[4]=f2b(x1.x*0.5f); fr[5]=f2b(x1.y*0.5f);
          fr[6]=f2b(x1.z*0.5f); fr[7]=f2b(x1.w*0.5f);
          bfrag[m][nt][kk] = fr;
          wpk[((m*2 + nt)*4 + kk)*256 + h*64 + lane] = fr;
        }
      }

    // feat fragments for this lane's s-row
    bf16x8 af[4];
#pragma unroll
    for (int kk = 0; kk < 4; ++kk) {
      const float* p = feat_emb + sIdx*kH + kk*32 + g*8;
      const float4 x0 = *(const float4*)p;
      const float4 x1 = *(const float4*)(p + 4);
      bf16x8 fr;
      fr[0]=f2b(x0.x); fr[1]=f2b(x0.y); fr[2]=f2b(x0.z); fr[3]=f2b(x0.w);
      fr[4]=f2b(x1.x); fr[5]=f2b(x1.y); fr[6]=f2b(x1.z); fr[7]=f2b(x1.w);
      af[kk] = fr;
    }
    const f32x4 zero4 = {0.f,0.f,0.f,0.f};
#pragma unroll
    for (int nt = 0; nt < 2; ++nt) {
      f32x4 cq = zero4, ck = zero4, cv = zero4;
#pragma unroll
      for (int kk = 0; kk < 4; ++kk) {
        cq = __builtin_amdgcn_mfma_f32_16x16x32_bf16(bfrag[0][nt][kk], af[kk], cq, 0,0,0);
        ck = __builtin_amdgcn_mfma_f32_16x16x32_bf16(bfrag[1][nt][kk], af[kk], ck, 0,0,0);
        cv = __builtin_amdgcn_mfma_f32_16x16x32_bf16(af[kk], bfrag[2][nt][kk], cv, 0,0,0);
      }
      const float4 bq4 = *(const float4*)(bq + 32*h + 16*nt + 4*g);
      const float4 bk4 = *(const float4*)(bk + 32*h + 16*nt + 4*g);
      cq[0]+=bq4.x; cq[1]+=bq4.y; cq[2]+=bq4.z; cq[3]+=bq4.w;
      ck[0]+=bk4.x; ck[1]+=bk4.y; ck[2]+=bk4.z; ck[3]+=bk4.w;
      const float bvn = bv[32*h + 16*nt + l15];
      cv[0]+=bvn; cv[1]+=bvn; cv[2]+=bvn; cv[3]+=bvn;
      seeds[((0*2 + nt)*4 + h)*64 + lane] = cq;
      seeds[((1*2 + nt)*4 + h)*64 + lane] = ck;
      seeds[((2*2 + nt)*4 + h)*64 + lane] = cv;
    }
  } else {
    // streaming table conversion: 8 f32 -> bf16x8 per chunk
    bf16x8* tab = (bf16x8*)ws;
    const int stride = (kPrepBlocks - 1) * 256;
    for (int c = (blockIdx.x - 1) * 256 + tid; c < kTabChunks; c += stride) {
      const float4* p = (const float4*)num_emb + (size_t)c * 2;
      const float4 x0 = p[0], x1 = p[1];
      bf16x8 fr;
      fr[0]=f2b(x0.x); fr[1]=f2b(x0.y); fr[2]=f2b(x0.z); fr[3]=f2b(x0.w);
      fr[4]=f2b(x1.x); fr[5]=f2b(x1.y); fr[6]=f2b(x1.z); fr[7]=f2b(x1.w);
      tab[c] = fr;
    }
  }
}

// ---------------------------------------------------------------------------
// Main: zero-LDS, zero-barrier, zero-conversion gather, depth-2 pipelined.
// Wave == head. A-fragments ARE the bf16 table rows.
// ---------------------------------------------------------------------------
__global__ __launch_bounds__(256, 4)   // pin VGPR <= 128 (4 waves/SIMD)
void fsa_main(const int* __restrict__ hs, const unsigned char* __restrict__ ws,
              float* __restrict__ out)
{
  const int tid  = threadIdx.x;
  const int lane = tid & 63;
  const int h    = tid >> 6;     // wave == head
  const int l15  = lane & 15;
  const int g    = lane >> 4;
  const int sIdx = (l15 < 13) ? l15 : 12;   // pad lanes dup s=12 (masked later)
  const int row0 = blockIdx.x * kRowsPerBlk;

  const bf16x8* wpk   = (const bf16x8*)(ws + kWpkOff);
  const f32x4*  seeds = (const f32x4*) (ws + kSeedOff);

  // ---- all row indices up front ----
  int ixs[kRowsPerBlk];
#pragma unroll
  for (int r = 0; r < kRowsPerBlk; ++r) {
    int ix = hs[(row0 + r) * kS + sIdx];
    ixs[r] = (ix > -1) ? ix : (kVocab - 1);
  }

  // ---- pre-packed weights + seeds: coalesced 16B/lane loads ----
  bf16x8 bfrag[3][2][4];
#pragma unroll
  for (int m = 0; m < 3; ++m)
#pragma unroll
    for (int nt = 0; nt < 2; ++nt)
#pragma unroll
      for (int kk = 0; kk < 4; ++kk)
        bfrag[m][nt][kk] = wpk[((m*2 + nt)*4 + kk)*256 + h*64 + lane];

  f32x4 CtQ[2], CtK[2], Cv[2];
#pragma unroll
  for (int nt = 0; nt < 2; ++nt) {
    CtQ[nt] = seeds[((0*2 + nt)*4 + h)*64 + lane];
    CtK[nt] = seeds[((1*2 + nt)*4 + h)*64 + lane];
    Cv[nt]  = seeds[((2*2 + nt)*4 + h)*64 + lane];
  }

  const float rsc = 0.17677669529663687f;  // 1/sqrt(32)
  const bool tval = (l15 < 13);
  const f32x4 zero4 = {0.f,0.f,0.f,0.f};

  // per-row computation from a register A-fragment
  auto row_body = [&](int r, const bf16x8* a) {
    f32x4 accq[2], acck[2], accv[2];
#pragma unroll
    for (int nt = 0; nt < 2; ++nt) {
      f32x4 aq = CtQ[nt], ak = CtK[nt], av = Cv[nt];
#pragma unroll
      for (int kk = 0; kk < 4; ++kk) {
        aq = __builtin_amdgcn_mfma_f32_16x16x32_bf16(bfrag[0][nt][kk], a[kk], aq, 0,0,0);
        ak = __builtin_amdgcn_mfma_f32_16x16x32_bf16(bfrag[1][nt][kk], a[kk], ak, 0,0,0);
        av = __builtin_amdgcn_mfma_f32_16x16x32_bf16(a[kk], bfrag[2][nt][kk], av, 0,0,0);
      }
      accq[nt] = aq; acck[nt] = ak; accv[nt] = av;
    }

    // scores, register-only: S[s=4g+j][t=l15]
    const bf16x8 qp = pack8(accq[0], accq[1]);
    const bf16x8 kp = pack8(acck[0], acck[1]);
    f32x4 sc = __builtin_amdgcn_mfma_f32_16x16x32_bf16(qp, kp, zero4, 0,0,0);

    // softmax over t within 16-lane groups (no max-sub: |s| << 88)
    float wsum = 0.f;
#pragma unroll
    for (int j = 0; j < 4; ++j) {
      float e = tval ? __expf(sc[j] * rsc) : 0.f;
      float su = e;
#pragma unroll
      for (int d = 1; d < 16; d <<= 1) su += __shfl_xor(su, d, 16);
      float pv = e * __builtin_amdgcn_rcpf(su);
      if (4*g + j >= 13) pv = 0.f;   // pad s-rows out of the column sum
      wsum += pv;
    }
    wsum += __shfl_xor(wsum, 16);
    wsum += __shfl_xor(wsum, 32);
    wsum *= (1.0f/13.0f);            // w[t] in lane t (mod 16), mean folded

    float wj[4];
#pragma unroll
    for (int j = 0; j < 4; ++j) wj[j] = __shfl(wsum, 4*g + j, 16);

    float o0 = wj[0]*accv[0][0] + wj[1]*accv[0][1] + wj[2]*accv[0][2] + wj[3]*accv[0][3];
    float o1 = wj[0]*accv[1][0] + wj[1]*accv[1][1] + wj[2]*accv[1][2] + wj[3]*accv[1][3];
    o0 += __shfl_xor(o0, 16); o0 += __shfl_xor(o0, 32);
    o1 += __shfl_xor(o1, 16); o1 += __shfl_xor(o1, 32);
    if (lane < 32)
      out[(size_t)(row0 + r) * kH + 32*h + lane] = (lane < 16) ? o0 : o1;
  };

  // ---- depth-2 software pipeline: two named buffers (static indexing) ----
  bf16x8 nbA[4], nbB[4];
#pragma unroll
  for (int kk = 0; kk < 4; ++kk)
    nbA[kk] = *(const bf16x8*)(ws + (size_t)ixs[0]*256 + kk*64 + g*16);
#pragma unroll
  for (int kk = 0; kk < 4; ++kk)
    nbB[kk] = *(const bf16x8*)(ws + (size_t)ixs[1]*256 + kk*64 + g*16);

#pragma unroll
  for (int rp = 0; rp < kRowsPerBlk/2; ++rp) {
    {
      const int r = 2*rp;
      bf16x8 a[4];
#pragma unroll
      for (int kk = 0; kk < 4; ++kk) a[kk] = nbA[kk];
      if (r + 2 < kRowsPerBlk) {
#pragma unroll
        for (int kk = 0; kk < 4; ++kk)
          nbA[kk] = *(const bf16x8*)(ws + (size_t)ixs[r+2]*256 + kk*64 + g*16);
      }
      row_body(r, a);
    }
    {
      const int r = 2*rp + 1;
      bf16x8 a[4];
#pragma unroll
      for (int kk = 0; kk < 4; ++kk) a[kk] = nbB[kk];
      if (r + 2 < kRowsPerBlk) {
#pragma unroll
        for (int kk = 0; kk < 4; ++kk)
          nbB[kk] = *(const bf16x8*)(ws + (size_t)ixs[r+2]*256 + kk*64 + g*16);
      }
      row_body(r, a);
    }
  }
}

// ---------------------------------------------------------------------------
// Fallback (ws too small): round-5 kernel, verified passing.
// ---------------------------------------------------------------------------
__global__ __launch_bounds__(256, 2)
void fsa_fused4(const int* __restrict__ hs,
                const float* __restrict__ num_emb,
                const float* __restrict__ feat_emb,
                const float* __restrict__ Wq, const float* __restrict__ bq,
                const float* __restrict__ Wk, const float* __restrict__ bk,
                const float* __restrict__ Wv, const float* __restrict__ bv,
                float* __restrict__ out)
{
  const int tid  = threadIdx.x;
  const int lane = tid & 63;
  const int h    = tid >> 6;
  const int l15  = lane & 15;
  const int g    = lane >> 4;
  const int sIdx = (l15 < 13) ? l15 : 12;
  const int row0 = blockIdx.x * 4;

  int ixs[4];
#pragma unroll
  for (int r = 0; r < 4; ++r) {
    int ix = hs[(row0 + r) * kS + sIdx];
    ixs[r] = ((ix > -1) ? ix : (kVocab - 1)) * kH;
  }

  bf16x8 bfrag[3][2][4];
  {
    const float* Wmat[3] = {Wq, Wk, Wv};
#pragma unroll
    for (int m = 0; m < 3; ++m)
#pragma unroll
      for (int nt = 0; nt < 2; ++nt) {
        const int n = 32*h + 16*nt + l15;
#pragma unroll
        for (int kk = 0; kk < 4; ++kk) {
          const float* p = Wmat[m] + n * kH + kk*32 + g*8;
          const float4 x0 = *(const float4*)p;
          const float4 x1 = *(const float4*)(p + 4);
          bf16x8 fr;
          fr[0]=f2b(x0.x*0.5f); fr[1]=f2b(x0.y*0.5f);
          fr[2]=f2b(x0.z*0.5f); fr[3]=f2b(x0.w*0.5f);
          fr[4]=f2b(x1.x*0.5f); fr[5]=f2b(x1.y*0.5f);
          fr[6]=f2b(x1.z*0.5f); fr[7]=f2b(x1.w*0.5f);
          bfrag[m][nt][kk] = fr;
        }
      }
  }

  float4 nb[8];
#pragma unroll
  for (int kk = 0; kk < 4; ++kk) {
    const float* p = num_emb + ixs[0] + kk*32 + g*8;
    nb[2*kk]   = *(const float4*)p;
    nb[2*kk+1] = *(const float4*)(p + 4);
  }

  f32x4 CtQ[2], CtK[2], Cv[2];
  {
    bf16x8 af[4];
#pragma unroll
    for (int kk = 0; kk < 4; ++kk) {
      const float* p = feat_emb + sIdx*kH + kk*32 + g*8;
      const float4 x0 = *(const float4*)p;
      const float4 x1 = *(const float4*)(p + 4);
      bf16x8 fr;
      fr[0]=f2b(x0.x); fr[1]=f2b(x0.y); fr[2]=f2b(x0.z); fr[3]=f2b(x0.w);
      fr[4]=f2b(x1.x); fr[5]=f2b(x1.y); fr[6]=f2b(x1.z); fr[7]=f2b(x1.w);
      af[kk] = fr;
    }
    const f32x4 zero4 = {0.f,0.f,0.f,0.f};
#pragma unroll
    for (int nt = 0; nt < 2; ++nt) {
      f32x4 cq = zero4, ck = zero4, cv = zero4;
#pragma unroll
      for (int kk = 0; kk < 4; ++kk) {
        cq = __builtin_amdgcn_mfma_f32_16x16x32_bf16(bfrag[0][nt][kk], af[kk], cq, 0,0,0);
        ck = __builtin_amdgcn_mfma_f32_16x16x32_bf16(bfrag[1][nt][kk], af[kk], ck, 0,0,0);
        cv = __builtin_amdgcn_mfma_f32_16x16x32_bf16(af[kk], bfrag[2][nt][kk], cv, 0,0,0);
      }
      const float4 bq4 = *(const float4*)(bq + 32*h + 16*nt + 4*g);
      const float4 bk4 = *(const float4*)(bk + 32*h + 16*nt + 4*g);
      cq[0]+=bq4.x; cq[1]+=bq4.y; cq[2]+=bq4.z; cq[3]+=bq4.w;
      ck[0]+=bk4.x; ck[1]+=bk4.y; ck[2]+=bk4.z; ck[3]+=bk4.w;
      const float bvn = bv[32*h + 16*nt + l15];
      cv[0]+=bvn; cv[1]+=bvn; cv[2]+=bvn; cv[3]+=bvn;
      CtQ[nt] = cq; CtK[nt] = ck; Cv[nt] = cv;
    }
  }

  const float rsc = 0.17677669529663687f;
  const bool tval = (l15 < 13);
  const f32x4 zero4 = {0.f,0.f,0.f,0.f};

#pragma unroll
  for (int r = 0; r < 4; ++r) {
    bf16x8 a[4];
#pragma unroll
    for (int kk = 0; kk < 4; ++kk) {
      const float4 x0 = nb[2*kk], x1 = nb[2*kk+1];
      bf16x8 fr;
      fr[0]=f2b(x0.x); fr[1]=f2b(x0.y); fr[2]=f2b(x0.z); fr[3]=f2b(x0.w);
      fr[4]=f2b(x1.x); fr[5]=f2b(x1.y); fr[6]=f2b(x1.z); fr[7]=f2b(x1.w);
      a[kk] = fr;
    }
    if (r + 1 < 4) {
#pragma unroll
      for (int kk = 0; kk < 4; ++kk) {
        const float* p = num_emb + ixs[r+1] + kk*32 + g*8;
        nb[2*kk]   = *(const float4*)p;
        nb[2*kk+1] = *(const float4*)(p + 4);
      }
    }

    f32x4 accq[2], acck[2], accv[2];
#pragma unroll
    for (int nt = 0; nt < 2; ++nt) {
      f32x4 aq = CtQ[nt], ak = CtK[nt], av = Cv[nt];
#pragma unroll
      for (int kk = 0; kk < 4; ++kk) {
        aq = __builtin_amdgcn_mfma_f32_16x16x32_bf16(bfrag[0][nt][kk], a[kk], aq, 0,0,0);
        ak = __builtin_amdgcn_mfma_f32_16x16x32_bf16(bfrag[1][nt][kk], a[kk], ak, 0,0,0);
        av = __builtin_amdgcn_mfma_f32_16x16x32_bf16(a[kk], bfrag[2][nt][kk], av, 0,0,0);
      }
      accq[nt] = aq; acck[nt] = ak; accv[nt] = av;
    }

    const bf16x8 qp = pack8(accq[0], accq[1]);
    const bf16x8 kp = pack8(acck[0], acck[1]);
    f32x4 sc = __builtin_amdgcn_mfma_f32_16x16x32_bf16(qp, kp, zero4, 0,0,0);

    float wsum = 0.f;
#pragma unroll
    for (int j = 0; j < 4; ++j) {
      float e = tval ? __expf(sc[j] * rsc) : 0.f;
      float su = e;
#pragma unroll
      for (int d = 1; d < 16; d <<= 1) su += __shfl_xor(su, d, 16);
      float pv = e * __builtin_amdgcn_rcpf(su);
      if (4*g + j >= 13) pv = 0.f;
      wsum += pv;
    }
    wsum += __shfl_xor(wsum, 16);
    wsum += __shfl_xor(wsum, 32);
    wsum *= (1.0f/13.0f);

    float wj[4];
#pragma unroll
    for (int j = 0; j < 4; ++j) wj[j] = __shfl(wsum, 4*g + j, 16);

    float o0 = wj[0]*accv[0][0] + wj[1]*accv[0][1] + wj[2]*accv[0][2] + wj[3]*accv[0][3];
    float o1 = wj[0]*accv[1][0] + wj[1]*accv[1][1] + wj[2]*accv[1][2] + wj[3]*accv[1][3];
    o0 += __shfl_xor(o0, 16); o0 += __shfl_xor(o0, 32);
    o1 += __shfl_xor(o1, 16); o1 += __shfl_xor(o1, 32);
    if (lane < 32)
      out[(size_t)(row0 + r) * kH + 32*h + lane] = (lane < 16) ? o0 : o1;
  }
}

} // namespace

extern "C" void kernel_launch(void* const* d_in, const int* in_sizes, int n_in,
                              void* d_out, int out_size, void* d_ws, size_t ws_size,
                              hipStream_t stream) {
  const int*   hs = (const int*)  d_in[0];
  const float* ne = (const float*)d_in[1];
  const float* fe = (const float*)d_in[2];
  const float* Wq = (const float*)d_in[3];
  const float* bq = (const float*)d_in[4];
  const float* Wk = (const float*)d_in[5];
  const float* bk = (const float*)d_in[6];
  const float* Wv = (const float*)d_in[7];
  const float* bv = (const float*)d_in[8];
  float* out = (float*)d_out;

  if (ws_size >= kWsNeed) {
    fsa_prep<<<dim3(kPrepBlocks), dim3(256), 0, stream>>>(
        ne, fe, Wq, bq, Wk, bk, Wv, bv, (unsigned char*)d_ws);
    fsa_main<<<dim3(kMainGrid), dim3(256), 0, stream>>>(
        hs, (const unsigned char*)d_ws, out);
  } else {
    fsa_fused4<<<dim3(4096), dim3(256), 0, stream>>>(
        hs, ne, fe, Wq, bq, Wk, bk, Wv, bv, out);
  }
}

// Round 11
// 147.731 us; speedup vs baseline: 1.9287x; 1.9287x over previous
//
#include <hip/hip_runtime.h>
#include <hip/hip_bf16.h>

namespace {

constexpr int kVocab = 100000;
constexpr int kS     = 13;     // sequence / n_feat
constexpr int kH     = 128;    // hidden
constexpr int kBatch = 16384;

// main kernel geometry
constexpr int kMainGrid   = 1024;
constexpr int kRowsPerBlk = kBatch / kMainGrid;   // 16

// prep geometry
constexpr int kPrepBlocks = 2049;                 // block 0: weights+seeds; 1..: table
constexpr int kTabChunks  = kVocab * kH / 8;      // 1,600,000 bf16x8 chunks

// ws layout (bytes)
constexpr size_t kTabBytes  = (size_t)kVocab * kH * 2;   // 25,600,000
constexpr size_t kWpkOff    = kTabBytes;
constexpr size_t kWpkBytes  = (size_t)3*2*4 * 256 * 16;  // 98,304
constexpr size_t kSeedOff   = kWpkOff + kWpkBytes;
constexpr size_t kSeedBytes = (size_t)3*2*4*64 * 16;     // 24,576
constexpr size_t kWsNeed    = kSeedOff + kSeedBytes;     // ~25.7 MB

typedef __attribute__((ext_vector_type(8))) short bf16x8;
typedef __attribute__((ext_vector_type(4))) float f32x4;

__device__ __forceinline__ short f2b(float f) {
  __hip_bfloat16 h = __float2bfloat16(f);
  return __builtin_bit_cast(short, h);
}
// pack two D-fragments (nt=0, nt=1) into one MFMA A/B-operand; k-slot 8g+i
// maps to d = 16*(i>>2)+4g+(i&3) — the same bijection on both operands of the
// scores MFMA, so the dot product is exact (verified R5/R8, absmax 4.9e-4).
__device__ __forceinline__ bf16x8 pack8(f32x4 lo, f32x4 hi) {
  bf16x8 r;
  r[0]=f2b(lo[0]); r[1]=f2b(lo[1]); r[2]=f2b(lo[2]); r[3]=f2b(lo[3]);
  r[4]=f2b(hi[0]); r[5]=f2b(hi[1]); r[6]=f2b(hi[2]); r[7]=f2b(hi[3]);
  return r;
}

// ---------------------------------------------------------------------------
// Prep: block 0 packs weight fragments (0.5 folded) + seeds (feat/2 @ W^T + b)
// once; blocks 1.. convert the vocab table to bf16 (streaming, coalesced).
// ---------------------------------------------------------------------------
__global__ __launch_bounds__(256)
void fsa_prep(const float* __restrict__ num_emb, const float* __restrict__ feat_emb,
              const float* __restrict__ Wq, const float* __restrict__ bq,
              const float* __restrict__ Wk, const float* __restrict__ bk,
              const float* __restrict__ Wv, const float* __restrict__ bv,
              unsigned char* __restrict__ ws)
{
  const int tid = threadIdx.x;
  if (blockIdx.x == 0) {
    const int lane = tid & 63, h = tid >> 6, l15 = lane & 15, g = lane >> 4;
    const int sIdx = (l15 < 13) ? l15 : 12;
    bf16x8* wpk   = (bf16x8*)(ws + kWpkOff);
    f32x4*  seeds = (f32x4*) (ws + kSeedOff);

    bf16x8 bfrag[3][2][4];
    const float* Wmat[3] = {Wq, Wk, Wv};
#pragma unroll
    for (int m = 0; m < 3; ++m)
#pragma unroll
      for (int nt = 0; nt < 2; ++nt) {
        const int n = 32*h + 16*nt + l15;
#pragma unroll
        for (int kk = 0; kk < 4; ++kk) {
          const float* p = Wmat[m] + n * kH + kk*32 + g*8;
          const float4 x0 = *(const float4*)p;
          const float4 x1 = *(const float4*)(p + 4);
          bf16x8 fr;
          fr[0]=f2b(x0.x*0.5f); fr[1]=f2b(x0.y*0.5f);
          fr[2]=f2b(x0.z*0.5f); fr[3]=f2b(x0.w*0.5f);
          fr[4]=f2b(x1.x*0.5f); fr[5]=f2b(x1.y*0.5f);
          fr[6]=f2b(x1.z*0.5f); fr[7]=f2b(x1.w*0.5f);
          bfrag[m][nt][kk] = fr;
          wpk[((m*2 + nt)*4 + kk)*256 + h*64 + lane] = fr;
        }
      }

    // feat fragments for this lane's s-row
    bf16x8 af[4];
#pragma unroll
    for (int kk = 0; kk < 4; ++kk) {
      const float* p = feat_emb + sIdx*kH + kk*32 + g*8;
      const float4 x0 = *(const float4*)p;
      const float4 x1 = *(const float4*)(p + 4);
      bf16x8 fr;
      fr[0]=f2b(x0.x); fr[1]=f2b(x0.y); fr[2]=f2b(x0.z); fr[3]=f2b(x0.w);
      fr[4]=f2b(x1.x); fr[5]=f2b(x1.y); fr[6]=f2b(x1.z); fr[7]=f2b(x1.w);
      af[kk] = fr;
    }
    const f32x4 zero4 = {0.f,0.f,0.f,0.f};
#pragma unroll
    for (int nt = 0; nt < 2; ++nt) {
      f32x4 cq = zero4, ck = zero4, cv = zero4;
#pragma unroll
      for (int kk = 0; kk < 4; ++kk) {
        cq = __builtin_amdgcn_mfma_f32_16x16x32_bf16(bfrag[0][nt][kk], af[kk], cq, 0,0,0);
        ck = __builtin_amdgcn_mfma_f32_16x16x32_bf16(bfrag[1][nt][kk], af[kk], ck, 0,0,0);
        cv = __builtin_amdgcn_mfma_f32_16x16x32_bf16(af[kk], bfrag[2][nt][kk], cv, 0,0,0);
      }
      const float4 bq4 = *(const float4*)(bq + 32*h + 16*nt + 4*g);
      const float4 bk4 = *(const float4*)(bk + 32*h + 16*nt + 4*g);
      cq[0]+=bq4.x; cq[1]+=bq4.y; cq[2]+=bq4.z; cq[3]+=bq4.w;
      ck[0]+=bk4.x; ck[1]+=bk4.y; ck[2]+=bk4.z; ck[3]+=bk4.w;
      const float bvn = bv[32*h + 16*nt + l15];
      cv[0]+=bvn; cv[1]+=bvn; cv[2]+=bvn; cv[3]+=bvn;
      seeds[((0*2 + nt)*4 + h)*64 + lane] = cq;
      seeds[((1*2 + nt)*4 + h)*64 + lane] = ck;
      seeds[((2*2 + nt)*4 + h)*64 + lane] = cv;
    }
  } else {
    // streaming table conversion: 8 f32 -> bf16x8 per chunk
    bf16x8* tab = (bf16x8*)ws;
    const int stride = (kPrepBlocks - 1) * 256;
    for (int c = (blockIdx.x - 1) * 256 + tid; c < kTabChunks; c += stride) {
      const float4* p = (const float4*)num_emb + (size_t)c * 2;
      const float4 x0 = p[0], x1 = p[1];
      bf16x8 fr;
      fr[0]=f2b(x0.x); fr[1]=f2b(x0.y); fr[2]=f2b(x0.z); fr[3]=f2b(x0.w);
      fr[4]=f2b(x1.x); fr[5]=f2b(x1.y); fr[6]=f2b(x1.z); fr[7]=f2b(x1.w);
      tab[c] = fr;
    }
  }
}

// Row body as a textual macro (no lambda — R10 showed lambda + bounds wrecks
// regalloc). Reads a[4], writes out; uses bfrag/CtQ/CtK/Cv/etc from scope.
#define ROW_BODY(RR, A)                                                        \
  do {                                                                         \
    f32x4 accq[2], acck[2], accv[2];                                           \
    _Pragma("unroll")                                                          \
    for (int nt = 0; nt < 2; ++nt) {                                           \
      f32x4 aq = CtQ[nt], ak = CtK[nt], av = Cv[nt];                           \
      _Pragma("unroll")                                                        \
      for (int kk = 0; kk < 4; ++kk) {                                         \
        aq = __builtin_amdgcn_mfma_f32_16x16x32_bf16(bfrag[0][nt][kk], (A)[kk], aq, 0,0,0); \
        ak = __builtin_amdgcn_mfma_f32_16x16x32_bf16(bfrag[1][nt][kk], (A)[kk], ak, 0,0,0); \
        av = __builtin_amdgcn_mfma_f32_16x16x32_bf16((A)[kk], bfrag[2][nt][kk], av, 0,0,0); \
      }                                                                        \
      accq[nt] = aq; acck[nt] = ak; accv[nt] = av;                             \
    }                                                                          \
    const bf16x8 qp = pack8(accq[0], accq[1]);                                 \
    const bf16x8 kp = pack8(acck[0], acck[1]);                                 \
    f32x4 sc = __builtin_amdgcn_mfma_f32_16x16x32_bf16(qp, kp, zero4, 0,0,0);  \
    float wsum = 0.f;                                                          \
    _Pragma("unroll")                                                          \
    for (int j = 0; j < 4; ++j) {                                              \
      float e = tval ? __expf(sc[j] * rsc) : 0.f;                              \
      float su = e;                                                            \
      _Pragma("unroll")                                                        \
      for (int d = 1; d < 16; d <<= 1) su += __shfl_xor(su, d, 16);            \
      float pv = e * __builtin_amdgcn_rcpf(su);                                \
      if (4*g + j >= 13) pv = 0.f;                                             \
      wsum += pv;                                                              \
    }                                                                          \
    wsum += __shfl_xor(wsum, 16);                                              \
    wsum += __shfl_xor(wsum, 32);                                              \
    wsum *= (1.0f/13.0f);                                                      \
    float wj[4];                                                               \
    _Pragma("unroll")                                                          \
    for (int j = 0; j < 4; ++j) wj[j] = __shfl(wsum, 4*g + j, 16);             \
    float o0 = wj[0]*accv[0][0] + wj[1]*accv[0][1] + wj[2]*accv[0][2] + wj[3]*accv[0][3]; \
    float o1 = wj[0]*accv[1][0] + wj[1]*accv[1][1] + wj[2]*accv[1][2] + wj[3]*accv[1][3]; \
    o0 += __shfl_xor(o0, 16); o0 += __shfl_xor(o0, 32);                        \
    o1 += __shfl_xor(o1, 16); o1 += __shfl_xor(o1, 32);                        \
    if (lane < 32)                                                             \
      out[(size_t)(row0 + (RR)) * kH + 32*h + lane] = (lane < 16) ? o0 : o1;   \
  } while (0)

// ---------------------------------------------------------------------------
// Main: zero-LDS, zero-barrier, zero-conversion gather, depth-2 pipelined.
// Wave == head. A-fragments ARE the bf16 table rows. NO min-waves bound
// (R4/R10: it causes catastrophic spills; VGPR ~120 keeps 4 waves/SIMD).
// ---------------------------------------------------------------------------
__global__ __launch_bounds__(256)
void fsa_main(const int* __restrict__ hs, const unsigned char* __restrict__ ws,
              float* __restrict__ out)
{
  const int tid  = threadIdx.x;
  const int lane = tid & 63;
  const int h    = tid >> 6;     // wave == head
  const int l15  = lane & 15;
  const int g    = lane >> 4;
  const int sIdx = (l15 < 13) ? l15 : 12;   // pad lanes dup s=12 (masked later)
  const int row0 = blockIdx.x * kRowsPerBlk;

  const bf16x8* wpk   = (const bf16x8*)(ws + kWpkOff);
  const f32x4*  seeds = (const f32x4*) (ws + kSeedOff);

  // ---- all row indices up front ----
  int ixs[kRowsPerBlk];
#pragma unroll
  for (int r = 0; r < kRowsPerBlk; ++r) {
    int ix = hs[(row0 + r) * kS + sIdx];
    ixs[r] = (ix > -1) ? ix : (kVocab - 1);
  }

  // ---- pre-packed weights + seeds: coalesced 16B/lane loads ----
  bf16x8 bfrag[3][2][4];
#pragma unroll
  for (int m = 0; m < 3; ++m)
#pragma unroll
    for (int nt = 0; nt < 2; ++nt)
#pragma unroll
      for (int kk = 0; kk < 4; ++kk)
        bfrag[m][nt][kk] = wpk[((m*2 + nt)*4 + kk)*256 + h*64 + lane];

  f32x4 CtQ[2], CtK[2], Cv[2];
#pragma unroll
  for (int nt = 0; nt < 2; ++nt) {
    CtQ[nt] = seeds[((0*2 + nt)*4 + h)*64 + lane];
    CtK[nt] = seeds[((1*2 + nt)*4 + h)*64 + lane];
    Cv[nt]  = seeds[((2*2 + nt)*4 + h)*64 + lane];
  }

  const float rsc = 0.17677669529663687f;  // 1/sqrt(32)
  const bool tval = (l15 < 13);
  const f32x4 zero4 = {0.f,0.f,0.f,0.f};

  // ---- depth-2 software pipeline: two named buffers (static indexing) ----
  bf16x8 nbA[4], nbB[4];
#pragma unroll
  for (int kk = 0; kk < 4; ++kk)
    nbA[kk] = *(const bf16x8*)(ws + (size_t)ixs[0]*256 + kk*64 + g*16);
#pragma unroll
  for (int kk = 0; kk < 4; ++kk)
    nbB[kk] = *(const bf16x8*)(ws + (size_t)ixs[1]*256 + kk*64 + g*16);

#pragma unroll
  for (int rp = 0; rp < kRowsPerBlk/2; ++rp) {
    {
      const int r = 2*rp;
      bf16x8 a[4];
#pragma unroll
      for (int kk = 0; kk < 4; ++kk) a[kk] = nbA[kk];
      if (r + 2 < kRowsPerBlk) {
#pragma unroll
        for (int kk = 0; kk < 4; ++kk)
          nbA[kk] = *(const bf16x8*)(ws + (size_t)ixs[r+2]*256 + kk*64 + g*16);
      }
      ROW_BODY(r, a);
    }
    {
      const int r = 2*rp + 1;
      bf16x8 a[4];
#pragma unroll
      for (int kk = 0; kk < 4; ++kk) a[kk] = nbB[kk];
      if (r + 2 < kRowsPerBlk) {
#pragma unroll
        for (int kk = 0; kk < 4; ++kk)
          nbB[kk] = *(const bf16x8*)(ws + (size_t)ixs[r+2]*256 + kk*64 + g*16);
      }
      ROW_BODY(r, a);
    }
  }
}

// ---------------------------------------------------------------------------
// Fallback (ws too small): round-5 kernel, verified passing.
// ---------------------------------------------------------------------------
__global__ __launch_bounds__(256, 2)
void fsa_fused4(const int* __restrict__ hs,
                const float* __restrict__ num_emb,
                const float* __restrict__ feat_emb,
                const float* __restrict__ Wq, const float* __restrict__ bq,
                const float* __restrict__ Wk, const float* __restrict__ bk,
                const float* __restrict__ Wv, const float* __restrict__ bv,
                float* __restrict__ out)
{
  const int tid  = threadIdx.x;
  const int lane = tid & 63;
  const int h    = tid >> 6;
  const int l15  = lane & 15;
  const int g    = lane >> 4;
  const int sIdx = (l15 < 13) ? l15 : 12;
  const int row0 = blockIdx.x * 4;

  int ixs[4];
#pragma unroll
  for (int r = 0; r < 4; ++r) {
    int ix = hs[(row0 + r) * kS + sIdx];
    ixs[r] = ((ix > -1) ? ix : (kVocab - 1)) * kH;
  }

  bf16x8 bfrag[3][2][4];
  {
    const float* Wmat[3] = {Wq, Wk, Wv};
#pragma unroll
    for (int m = 0; m < 3; ++m)
#pragma unroll
      for (int nt = 0; nt < 2; ++nt) {
        const int n = 32*h + 16*nt + l15;
#pragma unroll
        for (int kk = 0; kk < 4; ++kk) {
          const float* p = Wmat[m] + n * kH + kk*32 + g*8;
          const float4 x0 = *(const float4*)p;
          const float4 x1 = *(const float4*)(p + 4);
          bf16x8 fr;
          fr[0]=f2b(x0.x*0.5f); fr[1]=f2b(x0.y*0.5f);
          fr[2]=f2b(x0.z*0.5f); fr[3]=f2b(x0.w*0.5f);
          fr[4]=f2b(x1.x*0.5f); fr[5]=f2b(x1.y*0.5f);
          fr[6]=f2b(x1.z*0.5f); fr[7]=f2b(x1.w*0.5f);
          bfrag[m][nt][kk] = fr;
        }
      }
  }

  float4 nb[8];
#pragma unroll
  for (int kk = 0; kk < 4; ++kk) {
    const float* p = num_emb + ixs[0] + kk*32 + g*8;
    nb[2*kk]   = *(const float4*)p;
    nb[2*kk+1] = *(const float4*)(p + 4);
  }

  f32x4 CtQ[2], CtK[2], Cv[2];
  {
    bf16x8 af[4];
#pragma unroll
    for (int kk = 0; kk < 4; ++kk) {
      const float* p = feat_emb + sIdx*kH + kk*32 + g*8;
      const float4 x0 = *(const float4*)p;
      const float4 x1 = *(const float4*)(p + 4);
      bf16x8 fr;
      fr[0]=f2b(x0.x); fr[1]=f2b(x0.y); fr[2]=f2b(x0.z); fr[3]=f2b(x0.w);
      fr[4]=f2b(x1.x); fr[5]=f2b(x1.y); fr[6]=f2b(x1.z); fr[7]=f2b(x1.w);
      af[kk] = fr;
    }
    const f32x4 zero4 = {0.f,0.f,0.f,0.f};
#pragma unroll
    for (int nt = 0; nt < 2; ++nt) {
      f32x4 cq = zero4, ck = zero4, cv = zero4;
#pragma unroll
      for (int kk = 0; kk < 4; ++kk) {
        cq = __builtin_amdgcn_mfma_f32_16x16x32_bf16(bfrag[0][nt][kk], af[kk], cq, 0,0,0);
        ck = __builtin_amdgcn_mfma_f32_16x16x32_bf16(bfrag[1][nt][kk], af[kk], ck, 0,0,0);
        cv = __builtin_amdgcn_mfma_f32_16x16x32_bf16(af[kk], bfrag[2][nt][kk], cv, 0,0,0);
      }
      const float4 bq4 = *(const float4*)(bq + 32*h + 16*nt + 4*g);
      const float4 bk4 = *(const float4*)(bk + 32*h + 16*nt + 4*g);
      cq[0]+=bq4.x; cq[1]+=bq4.y; cq[2]+=bq4.z; cq[3]+=bq4.w;
      ck[0]+=bk4.x; ck[1]+=bk4.y; ck[2]+=bk4.z; ck[3]+=bk4.w;
      const float bvn = bv[32*h + 16*nt + l15];
      cv[0]+=bvn; cv[1]+=bvn; cv[2]+=bvn; cv[3]+=bvn;
      CtQ[nt] = cq; CtK[nt] = ck; Cv[nt] = cv;
    }
  }

  const float rsc = 0.17677669529663687f;
  const bool tval = (l15 < 13);
  const f32x4 zero4 = {0.f,0.f,0.f,0.f};

#pragma unroll
  for (int r = 0; r < 4; ++r) {
    bf16x8 a[4];
#pragma unroll
    for (int kk = 0; kk < 4; ++kk) {
      const float4 x0 = nb[2*kk], x1 = nb[2*kk+1];
      bf16x8 fr;
      fr[0]=f2b(x0.x); fr[1]=f2b(x0.y); fr[2]=f2b(x0.z); fr[3]=f2b(x0.w);
      fr[4]=f2b(x1.x); fr[5]=f2b(x1.y); fr[6]=f2b(x1.z); fr[7]=f2b(x1.w);
      a[kk] = fr;
    }
    if (r + 1 < 4) {
#pragma unroll
      for (int kk = 0; kk < 4; ++kk) {
        const float* p = num_emb + ixs[r+1] + kk*32 + g*8;
        nb[2*kk]   = *(const float4*)p;
        nb[2*kk+1] = *(const float4*)(p + 4);
      }
    }

    f32x4 accq[2], acck[2], accv[2];
#pragma unroll
    for (int nt = 0; nt < 2; ++nt) {
      f32x4 aq = CtQ[nt], ak = CtK[nt], av = Cv[nt];
#pragma unroll
      for (int kk = 0; kk < 4; ++kk) {
        aq = __builtin_amdgcn_mfma_f32_16x16x32_bf16(bfrag[0][nt][kk], a[kk], aq, 0,0,0);
        ak = __builtin_amdgcn_mfma_f32_16x16x32_bf16(bfrag[1][nt][kk], a[kk], ak, 0,0,0);
        av = __builtin_amdgcn_mfma_f32_16x16x32_bf16(a[kk], bfrag[2][nt][kk], av, 0,0,0);
      }
      accq[nt] = aq; acck[nt] = ak; accv[nt] = av;
    }

    const bf16x8 qp = pack8(accq[0], accq[1]);
    const bf16x8 kp = pack8(acck[0], acck[1]);
    f32x4 sc = __builtin_amdgcn_mfma_f32_16x16x32_bf16(qp, kp, zero4, 0,0,0);

    float wsum = 0.f;
#pragma unroll
    for (int j = 0; j < 4; ++j) {
      float e = tval ? __expf(sc[j] * rsc) : 0.f;
      float su = e;
#pragma unroll
      for (int d = 1; d < 16; d <<= 1) su += __shfl_xor(su, d, 16);
      float pv = e * __builtin_amdgcn_rcpf(su);
      if (4*g + j >= 13) pv = 0.f;
      wsum += pv;
    }
    wsum += __shfl_xor(wsum, 16);
    wsum += __shfl_xor(wsum, 32);
    wsum *= (1.0f/13.0f);

    float wj[4];
#pragma unroll
    for (int j = 0; j < 4; ++j) wj[j] = __shfl(wsum, 4*g + j, 16);

    float o0 = wj[0]*accv[0][0] + wj[1]*accv[0][1] + wj[2]*accv[0][2] + wj[3]*accv[0][3];
    float o1 = wj[0]*accv[1][0] + wj[1]*accv[1][1] + wj[2]*accv[1][2] + wj[3]*accv[1][3];
    o0 += __shfl_xor(o0, 16); o0 += __shfl_xor(o0, 32);
    o1 += __shfl_xor(o1, 16); o1 += __shfl_xor(o1, 32);
    if (lane < 32)
      out[(size_t)(row0 + r) * kH + 32*h + lane] = (lane < 16) ? o0 : o1;
  }
}

} // namespace

extern "C" void kernel_launch(void* const* d_in, const int* in_sizes, int n_in,
                              void* d_out, int out_size, void* d_ws, size_t ws_size,
                              hipStream_t stream) {
  const int*   hs = (const int*)  d_in[0];
  const float* ne = (const float*)d_in[1];
  const float* fe = (const float*)d_in[2];
  const float* Wq = (const float*)d_in[3];
  const float* bq = (const float*)d_in[4];
  const float* Wk = (const float*)d_in[5];
  const float* bk = (const float*)d_in[6];
  const float* Wv = (const float*)d_in[7];
  const float* bv = (const float*)d_in[8];
  float* out = (float*)d_out;

  if (ws_size >= kWsNeed) {
    fsa_prep<<<dim3(kPrepBlocks), dim3(256), 0, stream>>>(
        ne, fe, Wq, bq, Wk, bk, Wv, bv, (unsigned char*)d_ws);
    fsa_main<<<dim3(kMainGrid), dim3(256), 0, stream>>>(
        hs, (const unsigned char*)d_ws, out);
  } else {
    fsa_fused4<<<dim3(4096), dim3(256), 0, stream>>>(
        hs, ne, fe, Wq, bq, Wk, bk, Wv, bv, out);
  }
}